// Round 6
// baseline (212.856 us; speedup 1.0000x reference)
//
#include <hip/hip_runtime.h>
#include <math.h>

#define NODE_IN 64
#define NODE_OUT 96
#define EDGE_IN 16
#define EDGE_OUT 64
#define ACC_W 80          // NODE_IN + EDGE_IN
#define NB 500            // graphs
#define FPD 2048
#define FPE 128
#define XDIM 288          // 160 + 128
#define BN_EPS 1e-5f
#define HP 32             // per-graph counter padding (32 ints = 128 B line)

// ---------------- K1: edge graph keys + per-graph edge histogram (padded) ----
__global__ __launch_bounds__(256) void key_hist(
    const int* __restrict__ dst, const int* __restrict__ gids,
    int* __restrict__ gkey, int* __restrict__ histP, int E)
{
    __shared__ int h[NB];
    for (int i = threadIdx.x; i < NB; i += 256) h[i] = 0;
    __syncthreads();
    const int stride = gridDim.x * 256;
    for (int e = blockIdx.x * 256 + threadIdx.x; e < E; e += stride) {
        const int g = gids[dst[e]];
        gkey[e] = g;
        atomicAdd(&h[g], 1);
    }
    __syncthreads();
    for (int i = threadIdx.x; i < NB; i += 256)
        if (h[i]) atomicAdd(&histP[i * HP], h[i]);
}

// ---------------- K2: exclusive prefix sum over 500 padded counts ------------
__global__ __launch_bounds__(512) void scan_kernel(
    const int* __restrict__ histP, int* __restrict__ offs, int* __restrict__ cursP)
{
    __shared__ int s[512];
    const int t = threadIdx.x;
    const int v0 = (t < NB) ? histP[t * HP] : 0;
    s[t] = v0;
    __syncthreads();
    for (int d = 1; d < 512; d <<= 1) {
        const int v = (t >= d) ? s[t - d] : 0;
        __syncthreads();
        s[t] += v;
        __syncthreads();
    }
    if (t < NB) {
        offs[t] = s[t] - v0;
        cursP[t * HP] = s[t] - v0;
    }
}

// ---------------- K3: bucket edges by graph (block-aggregated atomics) -------
__global__ __launch_bounds__(256) void scatter_kernel(
    const int* __restrict__ gkey, const int* __restrict__ src,
    int* __restrict__ cursP, int* __restrict__ ssrc, int* __restrict__ seid, int E)
{
    __shared__ int h[NB];
    __shared__ int base[NB];
    const int t = threadIdx.x;
    for (int i = t; i < NB; i += 256) h[i] = 0;
    __syncthreads();

    const int e0 = blockIdx.x * 1024;
    int g4[4], lr4[4];
    #pragma unroll
    for (int i = 0; i < 4; ++i) {
        const int e = e0 + i * 256 + t;
        g4[i] = -1; lr4[i] = 0;
        if (e < E) {
            g4[i] = gkey[e];
            lr4[i] = atomicAdd(&h[g4[i]], 1);   // local rank within block
        }
    }
    __syncthreads();
    for (int i = t; i < NB; i += 256)
        base[i] = (h[i] > 0) ? atomicAdd(&cursP[i * HP], h[i]) : 0;
    __syncthreads();
    #pragma unroll
    for (int i = 0; i < 4; ++i) {
        const int e = e0 + i * 256 + t;
        if (g4[i] >= 0) {
            const int p = base[g4[i]] + lr4[i];
            ssrc[p] = src[e];
            seid[p] = e;
        }
    }
}

// ---------------- K4: per-graph register accumulation + mol GEMM + softmax ---
__global__ __launch_bounds__(256) void graph_accum(
    const int* __restrict__ ssrc, const int* __restrict__ seid,
    const float* __restrict__ nf, const float* __restrict__ ef,
    const int* __restrict__ offs, const int* __restrict__ histP,
    const float* __restrict__ Wm, const float* __restrict__ bm,
    const float* __restrict__ We, const float* __restrict__ be,
    float* __restrict__ xbuf, int E)
{
    const int g = blockIdx.x;
    const int t = threadIdx.x;
    const int lane = t & 63;
    const int w = t >> 6;
    const int start = offs[g];
    const int cnt = histP[g * HP];
    const int end = start + cnt;
    const int q = lane >> 4, c = lane & 15;

    __shared__ float sacc[4][ACC_W];
    __shared__ float accRow[ACC_W];
    __shared__ float red[256];

    float nacc = 0.f;   // node part: this lane owns feature column `lane`
    float eacc = 0.f;   // edge part: column c, quarter q

    for (int p0 = start + w * 64; p0 < end; p0 += 256) {
        const int lim = min(64, end - p0);
        const int sv = ssrc[min(p0 + lane, E - 1)];
        const int ev = seid[min(p0 + lane, E - 1)];

        // node rows: 16 independent gather loads in flight, register adds
        #pragma unroll
        for (int u0 = 0; u0 < 64; u0 += 16) {
            float v[16];
            #pragma unroll
            for (int u = 0; u < 16; ++u) {
                const int s = __builtin_amdgcn_readlane(sv, u0 + u);
                v[u] = nf[(size_t)s * NODE_IN + lane];
            }
            #pragma unroll
            for (int u = 0; u < 16; ++u)
                nacc += (u0 + u < lim) ? v[u] : 0.f;
        }

        // edge rows: 4 edges x 16 cols per step, 8-deep pipelined
        #pragma unroll
        for (int u0 = 0; u0 < 16; u0 += 8) {
            float w8[8];
            int idx8[8];
            #pragma unroll
            for (int u = 0; u < 8; ++u) {
                const int idx = (u0 + u) * 4 + q;
                const int eid = __shfl(ev, idx);
                idx8[u] = idx;
                w8[u] = ef[(size_t)eid * EDGE_IN + c];
            }
            #pragma unroll
            for (int u = 0; u < 8; ++u)
                eacc += (idx8[u] < lim) ? w8[u] : 0.f;
        }
    }

    if (lane < NODE_IN) sacc[w][lane] = nacc;
    eacc += __shfl_xor(eacc, 16);
    eacc += __shfl_xor(eacc, 32);
    if (lane < EDGE_IN) sacc[w][NODE_IN + lane] = eacc;
    __syncthreads();
    if (t < ACC_W) accRow[t] = (sacc[0][t] + sacc[1][t]) + (sacc[2][t] + sacc[3][t]);
    __syncthreads();

    // tiny GEMMs: [80] -> [160] molrow, plus count-scaled biases
    const float cntf = (float)cnt;
    float mr = 0.f;
    if (t < 96) {
        float m2 = 0.f;
        for (int k = 0; k < NODE_IN; ++k) m2 = fmaf(accRow[k], Wm[k * NODE_OUT + t], m2);
        mr = m2 + cntf * bm[t];
    } else if (t < 160) {
        const int j = t - 96;
        float m2 = 0.f;
        for (int k = 0; k < EDGE_IN; ++k) m2 = fmaf(accRow[NODE_IN + k], We[k * EDGE_OUT + j], m2);
        mr = m2 + cntf * be[j];
    }

    // softmax over the 160 mol columns
    red[t] = (t < 160) ? mr : -1e30f;
    __syncthreads();
    for (int st = 128; st > 0; st >>= 1) {
        if (t < st) red[t] = fmaxf(red[t], red[t + st]);
        __syncthreads();
    }
    const float mx = red[0];
    __syncthreads();
    const float evx = (t < 160) ? expf(mr - mx) : 0.f;
    red[t] = evx;
    __syncthreads();
    for (int st = 128; st > 0; st >>= 1) {
        if (t < st) red[t] += red[t + st];
        __syncthreads();
    }
    if (t < 160) xbuf[(size_t)g * XDIM + t] = evx / red[0];
}

// ---------------- K5: fingerprint encoder (row-stationary broadcast) ---------
// 125 blocks x 4 rows; 256 threads = 128 cols x 2 K-halves. X via wave-uniform
// scalar loads; W coalesced, read once per (col,k) per block; halves combined
// through conflict-free [4][128] LDS.
__global__ __launch_bounds__(256) void fp_kernel(
    const float* __restrict__ fpv, const float* __restrict__ Wf,
    const float* __restrict__ bf, const float* __restrict__ gam,
    const float* __restrict__ bet, const float* __restrict__ mu,
    const float* __restrict__ var, float* __restrict__ xbuf)
{
    __shared__ float part[4][FPE];
    const int t = threadIdx.x;
    const int j  = t & 127;          // output column
    const int kh = t >> 7;           // K-half: 0 or 1
    const int r0 = blockIdx.x * 4;

    const float* __restrict__ xp0 = fpv + (size_t)(r0 + 0) * FPD + kh * 1024;
    const float* __restrict__ xp1 = fpv + (size_t)(r0 + 1) * FPD + kh * 1024;
    const float* __restrict__ xp2 = fpv + (size_t)(r0 + 2) * FPD + kh * 1024;
    const float* __restrict__ xp3 = fpv + (size_t)(r0 + 3) * FPD + kh * 1024;
    const float* __restrict__ wp  = Wf + (size_t)kh * 1024 * FPE + j;

    float a0 = 0.f, a1 = 0.f, a2 = 0.f, a3 = 0.f;
    for (int k = 0; k < 1024; k += 8) {
        #pragma unroll
        for (int u = 0; u < 8; ++u) {
            const float w = wp[(size_t)(k + u) * FPE];
            a0 = fmaf(xp0[k + u], w, a0);
            a1 = fmaf(xp1[k + u], w, a1);
            a2 = fmaf(xp2[k + u], w, a2);
            a3 = fmaf(xp3[k + u], w, a3);
        }
    }
    if (kh == 1) {
        part[0][j] = a0; part[1][j] = a1; part[2][j] = a2; part[3][j] = a3;
    }
    __syncthreads();
    if (kh == 0) {
        a0 += part[0][j]; a1 += part[1][j]; a2 += part[2][j]; a3 += part[3][j];
        const float sc = rsqrtf(var[j] + BN_EPS) * gam[j];
        const float sh = bet[j] - mu[j] * sc;
        const float bj = bf[j];
        xbuf[(size_t)(r0 + 0) * XDIM + 160 + j] = fmaxf(fmaf(a0 + bj, sc, sh), 0.f);
        xbuf[(size_t)(r0 + 1) * XDIM + 160 + j] = fmaxf(fmaf(a1 + bj, sc, sh), 0.f);
        xbuf[(size_t)(r0 + 2) * XDIM + 160 + j] = fmaxf(fmaf(a2 + bj, sc, sh), 0.f);
        xbuf[(size_t)(r0 + 3) * XDIM + 160 + j] = fmaxf(fmaf(a3 + bj, sc, sh), 0.f);
    }
}

// ---------------- K6-K8: row-stationary broadcast FFN ------------------------
template<int NC>
__global__ __launch_bounds__(256) void ffn_bcast(
    const float* __restrict__ X, const float* __restrict__ W,
    const float* __restrict__ bias, float* __restrict__ Y,
    int Bv, int Ni, int No, int doRelu)
{
    const int t = threadIdx.x;
    const int r0 = blockIdx.x * 4;
    const float* __restrict__ xp0 = X + (size_t)r0 * Ni;
    const float* __restrict__ xp1 = X + (size_t)min(r0 + 1, Bv - 1) * Ni;
    const float* __restrict__ xp2 = X + (size_t)min(r0 + 2, Bv - 1) * Ni;
    const float* __restrict__ xp3 = X + (size_t)min(r0 + 3, Bv - 1) * Ni;

    float acc0[NC] = {}, acc1[NC] = {}, acc2[NC] = {}, acc3[NC] = {};

    for (int k = 0; k < Ni; k += 8) {
        #pragma unroll
        for (int u = 0; u < 8; ++u) {
            const float x0 = xp0[k + u];
            const float x1 = xp1[k + u];
            const float x2 = xp2[k + u];
            const float x3 = xp3[k + u];
            #pragma unroll
            for (int c = 0; c < NC; ++c) {
                const float w = W[(size_t)(k + u) * No + c * 256 + t];
                acc0[c] = fmaf(x0, w, acc0[c]);
                acc1[c] = fmaf(x1, w, acc1[c]);
                acc2[c] = fmaf(x2, w, acc2[c]);
                acc3[c] = fmaf(x3, w, acc3[c]);
            }
        }
    }

    #pragma unroll
    for (int c = 0; c < NC; ++c) {
        const int col = c * 256 + t;
        const float bv = bias[col];
        float o0 = acc0[c] + bv, o1 = acc1[c] + bv;
        float o2 = acc2[c] + bv, o3 = acc3[c] + bv;
        if (doRelu) {
            o0 = fmaxf(o0, 0.f); o1 = fmaxf(o1, 0.f);
            o2 = fmaxf(o2, 0.f); o3 = fmaxf(o3, 0.f);
        }
        Y[(size_t)r0 * No + col] = o0;
        if (r0 + 1 < Bv) Y[(size_t)(r0 + 1) * No + col] = o1;
        if (r0 + 2 < Bv) Y[(size_t)(r0 + 2) * No + col] = o2;
        if (r0 + 3 < Bv) Y[(size_t)(r0 + 3) * No + col] = o3;
    }
}

extern "C" void kernel_launch(void* const* d_in, const int* in_sizes, int n_in,
                              void* d_out, int out_size, void* d_ws, size_t ws_size,
                              hipStream_t stream)
{
    const float* node_feats = (const float*)d_in[0];
    const float* edge_feats = (const float*)d_in[1];
    const float* fpv        = (const float*)d_in[2];
    const int*   src        = (const int*)d_in[3];
    const int*   dst        = (const int*)d_in[4];
    const int*   gids       = (const int*)d_in[5];
    const float* Wm  = (const float*)d_in[6];
    const float* bm  = (const float*)d_in[7];
    const float* We  = (const float*)d_in[8];
    const float* be  = (const float*)d_in[9];
    const float* Wf  = (const float*)d_in[10];
    const float* bf  = (const float*)d_in[11];
    const float* gam = (const float*)d_in[12];
    const float* bet = (const float*)d_in[13];
    const float* mu  = (const float*)d_in[14];
    const float* var = (const float*)d_in[15];
    const float* W0  = (const float*)d_in[16];
    const float* b0  = (const float*)d_in[17];
    const float* W1  = (const float*)d_in[18];
    const float* b1  = (const float*)d_in[19];
    const float* W2  = (const float*)d_in[20];
    const float* b2  = (const float*)d_in[21];
    const int E = in_sizes[3];

    // workspace layout
    float* xbuf  = (float*)d_ws;                         // [500][288]
    float* h1    = xbuf + (size_t)NB * XDIM;             // [500][512]
    float* h2    = h1 + (size_t)NB * 512;                // [500][512]
    int*   gkey  = (int*)(h2 + (size_t)NB * 512);        // [E]
    int*   ssrc  = gkey + E;                              // [E]
    int*   seid  = ssrc + E;                              // [E]
    int*   histP = seid + E;                              // [NB*HP] padded
    int*   offs  = histP + NB * HP;                       // [NB]
    int*   cursP = offs + NB;                             // [NB*HP] padded

    hipMemsetAsync(histP, 0, NB * HP * sizeof(int), stream);
    hipLaunchKernelGGL(key_hist, dim3(256), dim3(256), 0, stream,
                       dst, gids, gkey, histP, E);
    hipLaunchKernelGGL(scan_kernel, dim3(1), dim3(512), 0, stream,
                       histP, offs, cursP);
    hipLaunchKernelGGL(scatter_kernel, dim3((E + 1023) / 1024), dim3(256), 0, stream,
                       gkey, src, cursP, ssrc, seid, E);
    hipLaunchKernelGGL(graph_accum, dim3(NB), dim3(256), 0, stream,
                       ssrc, seid, node_feats, edge_feats, offs, histP,
                       Wm, bm, We, be, xbuf, E);
    hipLaunchKernelGGL(fp_kernel, dim3(NB / 4), dim3(256), 0, stream,
                       fpv, Wf, bf, gam, bet, mu, var, xbuf);
    hipLaunchKernelGGL((ffn_bcast<2>), dim3((NB + 3) / 4), dim3(256), 0, stream,
                       xbuf, W0, b0, h1, NB, XDIM, 512, 1);
    hipLaunchKernelGGL((ffn_bcast<2>), dim3((NB + 3) / 4), dim3(256), 0, stream,
                       h1, W1, b1, h2, NB, 512, 512, 1);
    hipLaunchKernelGGL((ffn_bcast<1>), dim3((NB + 3) / 4), dim3(256), 0, stream,
                       h2, W2, b2, (float*)d_out, NB, 512, 256, 0);
}

// Round 7
// 168.738 us; speedup vs baseline: 1.2615x; 1.2615x over previous
//
#include <hip/hip_runtime.h>
#include <math.h>

#define NODE_IN 64
#define NODE_OUT 96
#define EDGE_IN 16
#define EDGE_OUT 64
#define ACC_W 80          // NODE_IN + EDGE_IN
#define NB 500            // graphs
#define FPD 2048
#define FPE 128
#define XDIM 288          // 160 + 128
#define BN_EPS 1e-5f
#define HB 2048           // edges per hist/scatter block

// ---------------- K1: per-block histogram + graph keys (no global atomics) ---
__global__ __launch_bounds__(256) void hist_kernel(
    const int* __restrict__ dst, const int* __restrict__ gids,
    int* __restrict__ gkey, int* __restrict__ pbh, int E)
{
    __shared__ int h[NB];
    const int t = threadIdx.x;
    for (int i = t; i < NB; i += 256) h[i] = 0;
    __syncthreads();
    const int e0 = blockIdx.x * HB;
    #pragma unroll
    for (int i = 0; i < HB / 256; ++i) {
        const int e = e0 + i * 256 + t;
        if (e < E) {
            const int g = gids[dst[e]];
            gkey[e] = g;
            atomicAdd(&h[g], 1);
        }
    }
    __syncthreads();
    for (int i = t; i < NB; i += 256)
        pbh[(size_t)blockIdx.x * NB + i] = h[i];
}

// ---------------- K2: offs[g] + deterministic per-block bases ---------------
__global__ __launch_bounds__(512) void scan2_kernel(
    const int* __restrict__ pbh, int* __restrict__ pbase,
    int* __restrict__ offs, int* __restrict__ tot, int nblk)
{
    __shared__ int s[512];
    const int t = threadIdx.x;   // graph id
    int total = 0;
    if (t < NB)
        for (int b = 0; b < nblk; ++b) total += pbh[(size_t)b * NB + t];
    const int v0 = (t < NB) ? total : 0;
    s[t] = v0;
    __syncthreads();
    for (int d = 1; d < 512; d <<= 1) {
        const int v = (t >= d) ? s[t - d] : 0;
        __syncthreads();
        s[t] += v;
        __syncthreads();
    }
    if (t < NB) {
        const int excl = s[t] - v0;
        offs[t] = excl;
        tot[t]  = v0;
        int run = excl;
        for (int b = 0; b < nblk; ++b) {
            pbase[(size_t)b * NB + t] = run;
            run += pbh[(size_t)b * NB + t];
        }
    }
}

// ---------------- K3: scatter with LDS-only atomics --------------------------
__global__ __launch_bounds__(256) void scatter2_kernel(
    const int* __restrict__ gkey, const int* __restrict__ src,
    const int* __restrict__ pbase,
    int* __restrict__ ssrc, int* __restrict__ seid, int E)
{
    __shared__ int h[NB];
    __shared__ int basel[NB];
    const int t = threadIdx.x;
    for (int i = t; i < NB; i += 256) {
        h[i] = 0;
        basel[i] = pbase[(size_t)blockIdx.x * NB + i];
    }
    __syncthreads();
    const int e0 = blockIdx.x * HB;
    #pragma unroll
    for (int i = 0; i < HB / 256; ++i) {
        const int e = e0 + i * 256 + t;
        if (e < E) {
            const int g = gkey[e];
            const int r = atomicAdd(&h[g], 1);
            const int p = basel[g] + r;
            ssrc[p] = src[e];
            seid[p] = e;
        }
    }
}

// ---------------- K4: per-graph register accumulation + mol GEMM + softmax ---
__global__ __launch_bounds__(1024) void graph_accum(
    const int* __restrict__ ssrc, const int* __restrict__ seid,
    const float* __restrict__ nf, const float* __restrict__ ef,
    const int* __restrict__ offs, const int* __restrict__ tot,
    const float* __restrict__ Wm, const float* __restrict__ bm,
    const float* __restrict__ We, const float* __restrict__ be,
    float* __restrict__ xbuf, int E)
{
    const int g = blockIdx.x;
    const int t = threadIdx.x;
    const int lane = t & 63;
    const int w = t >> 6;            // 16 waves
    const int start = offs[g];
    const int cnt = tot[g];
    const int end = start + cnt;
    const int q = lane >> 4, c = lane & 15;

    __shared__ float sacc[16][ACC_W];
    __shared__ float accRow[ACC_W];
    __shared__ float red[1024];

    float nacc = 0.f;   // node part: lane owns feature column `lane`
    float eacc = 0.f;   // edge part: column c, quarter q

    for (int p0 = start + w * 64; p0 < end; p0 += 1024) {
        const int lim = min(64, end - p0);
        const int sv = ssrc[min(p0 + lane, E - 1)];
        const int ev = seid[min(p0 + lane, E - 1)];

        #pragma unroll
        for (int u0 = 0; u0 < 64; u0 += 16) {
            float v[16];
            #pragma unroll
            for (int u = 0; u < 16; ++u) {
                const int s = __builtin_amdgcn_readlane(sv, u0 + u);
                v[u] = nf[(size_t)s * NODE_IN + lane];
            }
            #pragma unroll
            for (int u = 0; u < 16; ++u)
                nacc += (u0 + u < lim) ? v[u] : 0.f;
        }

        #pragma unroll
        for (int u0 = 0; u0 < 16; u0 += 8) {
            float w8[8];
            int idx8[8];
            #pragma unroll
            for (int u = 0; u < 8; ++u) {
                const int idx = (u0 + u) * 4 + q;
                const int eid = __shfl(ev, idx);
                idx8[u] = idx;
                w8[u] = ef[(size_t)eid * EDGE_IN + c];
            }
            #pragma unroll
            for (int u = 0; u < 8; ++u)
                eacc += (idx8[u] < lim) ? w8[u] : 0.f;
        }
    }

    if (lane < NODE_IN) sacc[w][lane] = nacc;
    eacc += __shfl_xor(eacc, 16);
    eacc += __shfl_xor(eacc, 32);
    if (lane < EDGE_IN) sacc[w][NODE_IN + lane] = eacc;
    __syncthreads();
    if (t < ACC_W) {
        float s = 0.f;
        #pragma unroll
        for (int w2 = 0; w2 < 16; ++w2) s += sacc[w2][t];
        accRow[t] = s;
    }
    __syncthreads();

    const float cntf = (float)cnt;
    float mr = 0.f;
    if (t < 96) {
        float m2 = 0.f;
        for (int k = 0; k < NODE_IN; ++k) m2 = fmaf(accRow[k], Wm[k * NODE_OUT + t], m2);
        mr = m2 + cntf * bm[t];
    } else if (t < 160) {
        const int j = t - 96;
        float m2 = 0.f;
        for (int k = 0; k < EDGE_IN; ++k) m2 = fmaf(accRow[NODE_IN + k], We[k * EDGE_OUT + j], m2);
        mr = m2 + cntf * be[j];
    }

    red[t] = (t < 160) ? mr : -1e30f;
    __syncthreads();
    for (int st = 512; st > 0; st >>= 1) {
        if (t < st) red[t] = fmaxf(red[t], red[t + st]);
        __syncthreads();
    }
    const float mx = red[0];
    __syncthreads();
    const float evx = (t < 160) ? expf(mr - mx) : 0.f;
    red[t] = evx;
    __syncthreads();
    for (int st = 512; st > 0; st >>= 1) {
        if (t < st) red[t] += red[t + st];
        __syncthreads();
    }
    if (t < 160) xbuf[(size_t)g * XDIM + t] = evx / red[0];
}

// ---------------- K5: fingerprint encoder, split-K in block ------------------
// 125 blocks x 1024 threads = 128 cols x 8 K-chunks of 256; 4 rows per block.
__global__ __launch_bounds__(1024) void fp_kernel(
    const float* __restrict__ fpv, const float* __restrict__ Wf,
    const float* __restrict__ bf, const float* __restrict__ gam,
    const float* __restrict__ bet, const float* __restrict__ mu,
    const float* __restrict__ var, float* __restrict__ xbuf)
{
    __shared__ float part[7][4][FPE];   // 14 KB
    const int t = threadIdx.x;
    const int j  = t & 127;
    const int kh = __builtin_amdgcn_readfirstlane(t >> 7);  // 0..7, wave-uniform
    const int r0 = blockIdx.x * 4;
    const int k0 = kh * 256;

    const float* __restrict__ xp0 = fpv + (size_t)(r0 + 0) * FPD + k0;
    const float* __restrict__ xp1 = fpv + (size_t)(r0 + 1) * FPD + k0;
    const float* __restrict__ xp2 = fpv + (size_t)(r0 + 2) * FPD + k0;
    const float* __restrict__ xp3 = fpv + (size_t)(r0 + 3) * FPD + k0;
    const float* __restrict__ wp  = Wf + (size_t)k0 * FPE + j;

    float a0 = 0.f, a1 = 0.f, a2 = 0.f, a3 = 0.f;
    for (int k = 0; k < 256; k += 8) {
        #pragma unroll
        for (int u = 0; u < 8; ++u) {
            const float w = wp[(size_t)(k + u) * FPE];
            a0 = fmaf(xp0[k + u], w, a0);
            a1 = fmaf(xp1[k + u], w, a1);
            a2 = fmaf(xp2[k + u], w, a2);
            a3 = fmaf(xp3[k + u], w, a3);
        }
    }
    if (kh > 0) {
        part[kh - 1][0][j] = a0; part[kh - 1][1][j] = a1;
        part[kh - 1][2][j] = a2; part[kh - 1][3][j] = a3;
    }
    __syncthreads();
    if (kh == 0) {
        #pragma unroll
        for (int qd = 0; qd < 7; ++qd) {
            a0 += part[qd][0][j]; a1 += part[qd][1][j];
            a2 += part[qd][2][j]; a3 += part[qd][3][j];
        }
        const float sc = rsqrtf(var[j] + BN_EPS) * gam[j];
        const float sh = bet[j] - mu[j] * sc;
        const float bj = bf[j];
        xbuf[(size_t)(r0 + 0) * XDIM + 160 + j] = fmaxf(fmaf(a0 + bj, sc, sh), 0.f);
        xbuf[(size_t)(r0 + 1) * XDIM + 160 + j] = fmaxf(fmaf(a1 + bj, sc, sh), 0.f);
        xbuf[(size_t)(r0 + 2) * XDIM + 160 + j] = fmaxf(fmaf(a2 + bj, sc, sh), 0.f);
        xbuf[(size_t)(r0 + 3) * XDIM + 160 + j] = fmaxf(fmaf(a3 + bj, sc, sh), 0.f);
    }
}

// ---------------- K6-K8: FFN, split-K in block --------------------------------
// 125 blocks x 1024 threads = NO cols x KS K-chunks; 4 rows per block.
template<int NO, int KS>
__global__ __launch_bounds__(1024) void ffn_split(
    const float* __restrict__ X, const float* __restrict__ W,
    const float* __restrict__ bias, float* __restrict__ Y,
    int Bv, int Ni, int doRelu)
{
    __shared__ float part[KS - 1][4][NO];
    const int t = threadIdx.x;
    const int col = t % NO;
    const int ks = __builtin_amdgcn_readfirstlane(t / NO);
    const int r0 = blockIdx.x * 4;
    const int kchunk = Ni / KS;
    const int k0 = ks * kchunk;

    const float* __restrict__ xp0 = X + (size_t)(r0 + 0) * Ni + k0;
    const float* __restrict__ xp1 = X + (size_t)(r0 + 1) * Ni + k0;
    const float* __restrict__ xp2 = X + (size_t)(r0 + 2) * Ni + k0;
    const float* __restrict__ xp3 = X + (size_t)(r0 + 3) * Ni + k0;
    const float* __restrict__ wp  = W + (size_t)k0 * NO + col;

    float a0 = 0.f, a1 = 0.f, a2 = 0.f, a3 = 0.f;
    for (int k = 0; k < kchunk; k += 8) {
        #pragma unroll
        for (int u = 0; u < 8; ++u) {
            const float w = wp[(size_t)(k + u) * NO];
            a0 = fmaf(xp0[k + u], w, a0);
            a1 = fmaf(xp1[k + u], w, a1);
            a2 = fmaf(xp2[k + u], w, a2);
            a3 = fmaf(xp3[k + u], w, a3);
        }
    }
    if (ks > 0) {
        part[ks - 1][0][col] = a0; part[ks - 1][1][col] = a1;
        part[ks - 1][2][col] = a2; part[ks - 1][3][col] = a3;
    }
    __syncthreads();
    if (ks == 0) {
        #pragma unroll
        for (int qd = 0; qd < KS - 1; ++qd) {
            a0 += part[qd][0][col]; a1 += part[qd][1][col];
            a2 += part[qd][2][col]; a3 += part[qd][3][col];
        }
        const float bv = bias[col];
        float o0 = a0 + bv, o1 = a1 + bv, o2 = a2 + bv, o3 = a3 + bv;
        if (doRelu) {
            o0 = fmaxf(o0, 0.f); o1 = fmaxf(o1, 0.f);
            o2 = fmaxf(o2, 0.f); o3 = fmaxf(o3, 0.f);
        }
        Y[(size_t)(r0 + 0) * NO + col] = o0;
        if (r0 + 1 < Bv) Y[(size_t)(r0 + 1) * NO + col] = o1;
        if (r0 + 2 < Bv) Y[(size_t)(r0 + 2) * NO + col] = o2;
        if (r0 + 3 < Bv) Y[(size_t)(r0 + 3) * NO + col] = o3;
    }
}

extern "C" void kernel_launch(void* const* d_in, const int* in_sizes, int n_in,
                              void* d_out, int out_size, void* d_ws, size_t ws_size,
                              hipStream_t stream)
{
    const float* node_feats = (const float*)d_in[0];
    const float* edge_feats = (const float*)d_in[1];
    const float* fpv        = (const float*)d_in[2];
    const int*   src        = (const int*)d_in[3];
    const int*   dst        = (const int*)d_in[4];
    const int*   gids       = (const int*)d_in[5];
    const float* Wm  = (const float*)d_in[6];
    const float* bm  = (const float*)d_in[7];
    const float* We  = (const float*)d_in[8];
    const float* be  = (const float*)d_in[9];
    const float* Wf  = (const float*)d_in[10];
    const float* bf  = (const float*)d_in[11];
    const float* gam = (const float*)d_in[12];
    const float* bet = (const float*)d_in[13];
    const float* mu  = (const float*)d_in[14];
    const float* var = (const float*)d_in[15];
    const float* W0  = (const float*)d_in[16];
    const float* b0  = (const float*)d_in[17];
    const float* W1  = (const float*)d_in[18];
    const float* b1  = (const float*)d_in[19];
    const float* W2  = (const float*)d_in[20];
    const float* b2  = (const float*)d_in[21];
    const int E = in_sizes[3];
    const int nblk = (E + HB - 1) / HB;

    // workspace layout
    float* xbuf  = (float*)d_ws;                          // [500][288]
    float* h1    = xbuf + (size_t)NB * XDIM;              // [500][512]
    float* h2    = h1 + (size_t)NB * 512;                 // [500][512]
    int*   gkey  = (int*)(h2 + (size_t)NB * 512);         // [E]
    int*   ssrc  = gkey + E;                               // [E]
    int*   seid  = ssrc + E;                               // [E]
    int*   pbh   = seid + E;                               // [nblk][NB]
    int*   pbase = pbh + (size_t)nblk * NB;                // [nblk][NB]
    int*   offs  = pbase + (size_t)nblk * NB;              // [NB]
    int*   tot   = offs + NB;                              // [NB]

    hipLaunchKernelGGL(hist_kernel, dim3(nblk), dim3(256), 0, stream,
                       dst, gids, gkey, pbh, E);
    hipLaunchKernelGGL(scan2_kernel, dim3(1), dim3(512), 0, stream,
                       pbh, pbase, offs, tot, nblk);
    hipLaunchKernelGGL(scatter2_kernel, dim3(nblk), dim3(256), 0, stream,
                       gkey, src, pbase, ssrc, seid, E);
    hipLaunchKernelGGL(graph_accum, dim3(NB), dim3(1024), 0, stream,
                       ssrc, seid, node_feats, edge_feats, offs, tot,
                       Wm, bm, We, be, xbuf, E);
    hipLaunchKernelGGL(fp_kernel, dim3(NB / 4), dim3(1024), 0, stream,
                       fpv, Wf, bf, gam, bet, mu, var, xbuf);
    hipLaunchKernelGGL((ffn_split<512, 2>), dim3((NB + 3) / 4), dim3(1024), 0, stream,
                       xbuf, W0, b0, h1, NB, XDIM, 1);
    hipLaunchKernelGGL((ffn_split<512, 2>), dim3((NB + 3) / 4), dim3(1024), 0, stream,
                       h1, W1, b1, h2, NB, 512, 1);
    hipLaunchKernelGGL((ffn_split<256, 4>), dim3((NB + 3) / 4), dim3(1024), 0, stream,
                       h2, W2, b2, (float*)d_out, NB, 512, 0);
}

// Round 8
// 113.608 us; speedup vs baseline: 1.8736x; 1.4853x over previous
//
#include <hip/hip_runtime.h>
#include <math.h>

#define NODE_IN 64
#define NODE_OUT 96
#define EDGE_IN 16
#define EDGE_OUT 64
#define ACC_W 80          // NODE_IN + EDGE_IN
#define NB 500            // graphs
#define FPD 2048
#define FPE 128
#define XDIM 288          // 160 + 128
#define BN_EPS 1e-5f
#define HB 2048           // edges per hist/scatter block

// ---------------- K1: per-block histogram + graph keys (no global atomics) ---
__global__ __launch_bounds__(256) void hist_kernel(
    const int* __restrict__ dst, const int* __restrict__ gids,
    int* __restrict__ gkey, int* __restrict__ pbh, int E)
{
    __shared__ int h[NB];
    const int t = threadIdx.x;
    for (int i = t; i < NB; i += 256) h[i] = 0;
    __syncthreads();
    const int e0 = blockIdx.x * HB;
    #pragma unroll
    for (int i = 0; i < HB / 256; ++i) {
        const int e = e0 + i * 256 + t;
        if (e < E) {
            const int g = gids[dst[e]];
            gkey[e] = g;
            atomicAdd(&h[g], 1);
        }
    }
    __syncthreads();
    for (int i = t; i < NB; i += 256)
        pbh[(size_t)blockIdx.x * NB + i] = h[i];
}

// ---------------- K2a: per-graph scan over blocks (500 blocks) ---------------
// block g: Hillis-Steele scan of pbh[0..nblk)[g] -> pcs (exclusive), gsum[g].
__global__ __launch_bounds__(256) void colscan_kernel(
    const int* __restrict__ pbh, int* __restrict__ pcs,
    int* __restrict__ gsum, int nblk)
{
    __shared__ int s[256];
    const int g = blockIdx.x;
    const int t = threadIdx.x;
    const int v0 = (t < nblk) ? pbh[(size_t)t * NB + g] : 0;
    s[t] = v0;
    __syncthreads();
    for (int d = 1; d < 256; d <<= 1) {
        const int v = (t >= d) ? s[t - d] : 0;
        __syncthreads();
        s[t] += v;
        __syncthreads();
    }
    if (t < nblk) pcs[(size_t)t * NB + g] = s[t] - v0;
    if (t == 255) gsum[g] = s[255];
}

// ---------------- K2b: scan over 500 graph totals ----------------------------
__global__ __launch_bounds__(512) void gscan_kernel(
    const int* __restrict__ gsum, int* __restrict__ offs, int* __restrict__ tot)
{
    __shared__ int s[512];
    const int t = threadIdx.x;
    const int v0 = (t < NB) ? gsum[t] : 0;
    s[t] = v0;
    __syncthreads();
    for (int d = 1; d < 512; d <<= 1) {
        const int v = (t >= d) ? s[t - d] : 0;
        __syncthreads();
        s[t] += v;
        __syncthreads();
    }
    if (t < NB) {
        offs[t] = s[t] - v0;
        tot[t]  = v0;
    }
}

// ---------------- K3: scatter with LDS-only atomics --------------------------
__global__ __launch_bounds__(256) void scatter2_kernel(
    const int* __restrict__ gkey, const int* __restrict__ src,
    const int* __restrict__ pcs, const int* __restrict__ offs,
    int* __restrict__ ssrc, int* __restrict__ seid, int E)
{
    __shared__ int h[NB];
    __shared__ int basel[NB];
    const int t = threadIdx.x;
    for (int i = t; i < NB; i += 256) {
        h[i] = 0;
        basel[i] = offs[i] + pcs[(size_t)blockIdx.x * NB + i];
    }
    __syncthreads();
    const int e0 = blockIdx.x * HB;
    #pragma unroll
    for (int i = 0; i < HB / 256; ++i) {
        const int e = e0 + i * 256 + t;
        if (e < E) {
            const int g = gkey[e];
            const int r = atomicAdd(&h[g], 1);
            const int p = basel[g] + r;
            ssrc[p] = src[e];
            seid[p] = e;
        }
    }
}

// ---------------- K4: per-graph register accumulation + mol GEMM + softmax ---
__global__ __launch_bounds__(1024) void graph_accum(
    const int* __restrict__ ssrc, const int* __restrict__ seid,
    const float* __restrict__ nf, const float* __restrict__ ef,
    const int* __restrict__ offs, const int* __restrict__ tot,
    const float* __restrict__ Wm, const float* __restrict__ bm,
    const float* __restrict__ We, const float* __restrict__ be,
    float* __restrict__ xbuf, int E)
{
    const int g = blockIdx.x;
    const int t = threadIdx.x;
    const int lane = t & 63;
    const int w = t >> 6;            // 16 waves
    const int start = offs[g];
    const int cnt = tot[g];
    const int end = start + cnt;
    const int q = lane >> 4, c = lane & 15;

    __shared__ float sacc[16][ACC_W];
    __shared__ float accRow[ACC_W];
    __shared__ float red[1024];

    float nacc = 0.f;   // node part: lane owns feature column `lane`
    float eacc = 0.f;   // edge part: column c, quarter q

    for (int p0 = start + w * 64; p0 < end; p0 += 1024) {
        const int lim = min(64, end - p0);
        const int sv = ssrc[min(p0 + lane, E - 1)];
        const int ev = seid[min(p0 + lane, E - 1)];

        #pragma unroll
        for (int u0 = 0; u0 < 64; u0 += 16) {
            float v[16];
            #pragma unroll
            for (int u = 0; u < 16; ++u) {
                const int s = __builtin_amdgcn_readlane(sv, u0 + u);
                v[u] = nf[(size_t)s * NODE_IN + lane];
            }
            #pragma unroll
            for (int u = 0; u < 16; ++u)
                nacc += (u0 + u < lim) ? v[u] : 0.f;
        }

        #pragma unroll
        for (int u0 = 0; u0 < 16; u0 += 8) {
            float w8[8];
            int idx8[8];
            #pragma unroll
            for (int u = 0; u < 8; ++u) {
                const int idx = (u0 + u) * 4 + q;
                const int eid = __shfl(ev, idx);
                idx8[u] = idx;
                w8[u] = ef[(size_t)eid * EDGE_IN + c];
            }
            #pragma unroll
            for (int u = 0; u < 8; ++u)
                eacc += (idx8[u] < lim) ? w8[u] : 0.f;
        }
    }

    if (lane < NODE_IN) sacc[w][lane] = nacc;
    eacc += __shfl_xor(eacc, 16);
    eacc += __shfl_xor(eacc, 32);
    if (lane < EDGE_IN) sacc[w][NODE_IN + lane] = eacc;
    __syncthreads();
    if (t < ACC_W) {
        float s = 0.f;
        #pragma unroll
        for (int w2 = 0; w2 < 16; ++w2) s += sacc[w2][t];
        accRow[t] = s;
    }
    __syncthreads();

    const float cntf = (float)cnt;
    float mr = 0.f;
    if (t < 96) {
        float m2 = 0.f;
        for (int k = 0; k < NODE_IN; ++k) m2 = fmaf(accRow[k], Wm[k * NODE_OUT + t], m2);
        mr = m2 + cntf * bm[t];
    } else if (t < 160) {
        const int j = t - 96;
        float m2 = 0.f;
        for (int k = 0; k < EDGE_IN; ++k) m2 = fmaf(accRow[NODE_IN + k], We[k * EDGE_OUT + j], m2);
        mr = m2 + cntf * be[j];
    }

    red[t] = (t < 160) ? mr : -1e30f;
    __syncthreads();
    for (int st = 512; st > 0; st >>= 1) {
        if (t < st) red[t] = fmaxf(red[t], red[t + st]);
        __syncthreads();
    }
    const float mx = red[0];
    __syncthreads();
    const float evx = (t < 160) ? expf(mr - mx) : 0.f;
    red[t] = evx;
    __syncthreads();
    for (int st = 512; st > 0; st >>= 1) {
        if (t < st) red[t] += red[t + st];
        __syncthreads();
    }
    if (t < 160) xbuf[(size_t)g * XDIM + t] = evx / red[0];
}

// ---------------- K5: fingerprint encoder, split-K in block ------------------
__global__ __launch_bounds__(1024) void fp_kernel(
    const float* __restrict__ fpv, const float* __restrict__ Wf,
    const float* __restrict__ bf, const float* __restrict__ gam,
    const float* __restrict__ bet, const float* __restrict__ mu,
    const float* __restrict__ var, float* __restrict__ xbuf)
{
    __shared__ float part[7][4][FPE];   // 14 KB
    const int t = threadIdx.x;
    const int j  = t & 127;
    const int kh = __builtin_amdgcn_readfirstlane(t >> 7);  // 0..7, wave-uniform
    const int r0 = blockIdx.x * 4;
    const int k0 = kh * 256;

    const float* __restrict__ xp0 = fpv + (size_t)(r0 + 0) * FPD + k0;
    const float* __restrict__ xp1 = fpv + (size_t)(r0 + 1) * FPD + k0;
    const float* __restrict__ xp2 = fpv + (size_t)(r0 + 2) * FPD + k0;
    const float* __restrict__ xp3 = fpv + (size_t)(r0 + 3) * FPD + k0;
    const float* __restrict__ wp  = Wf + (size_t)k0 * FPE + j;

    float a0 = 0.f, a1 = 0.f, a2 = 0.f, a3 = 0.f;
    for (int k = 0; k < 256; k += 8) {
        #pragma unroll
        for (int u = 0; u < 8; ++u) {
            const float w = wp[(size_t)(k + u) * FPE];
            a0 = fmaf(xp0[k + u], w, a0);
            a1 = fmaf(xp1[k + u], w, a1);
            a2 = fmaf(xp2[k + u], w, a2);
            a3 = fmaf(xp3[k + u], w, a3);
        }
    }
    if (kh > 0) {
        part[kh - 1][0][j] = a0; part[kh - 1][1][j] = a1;
        part[kh - 1][2][j] = a2; part[kh - 1][3][j] = a3;
    }
    __syncthreads();
    if (kh == 0) {
        #pragma unroll
        for (int qd = 0; qd < 7; ++qd) {
            a0 += part[qd][0][j]; a1 += part[qd][1][j];
            a2 += part[qd][2][j]; a3 += part[qd][3][j];
        }
        const float sc = rsqrtf(var[j] + BN_EPS) * gam[j];
        const float sh = bet[j] - mu[j] * sc;
        const float bj = bf[j];
        xbuf[(size_t)(r0 + 0) * XDIM + 160 + j] = fmaxf(fmaf(a0 + bj, sc, sh), 0.f);
        xbuf[(size_t)(r0 + 1) * XDIM + 160 + j] = fmaxf(fmaf(a1 + bj, sc, sh), 0.f);
        xbuf[(size_t)(r0 + 2) * XDIM + 160 + j] = fmaxf(fmaf(a2 + bj, sc, sh), 0.f);
        xbuf[(size_t)(r0 + 3) * XDIM + 160 + j] = fmaxf(fmaf(a3 + bj, sc, sh), 0.f);
    }
}

// ---------------- K6-K8: FFN, split-K in block --------------------------------
template<int NO, int KS>
__global__ __launch_bounds__(1024) void ffn_split(
    const float* __restrict__ X, const float* __restrict__ W,
    const float* __restrict__ bias, float* __restrict__ Y,
    int Bv, int Ni, int doRelu)
{
    __shared__ float part[KS - 1][4][NO];
    const int t = threadIdx.x;
    const int col = t % NO;
    const int ks = __builtin_amdgcn_readfirstlane(t / NO);
    const int r0 = blockIdx.x * 4;
    const int kchunk = Ni / KS;
    const int k0 = ks * kchunk;

    const float* __restrict__ xp0 = X + (size_t)(r0 + 0) * Ni + k0;
    const float* __restrict__ xp1 = X + (size_t)(r0 + 1) * Ni + k0;
    const float* __restrict__ xp2 = X + (size_t)(r0 + 2) * Ni + k0;
    const float* __restrict__ xp3 = X + (size_t)(r0 + 3) * Ni + k0;
    const float* __restrict__ wp  = W + (size_t)k0 * NO + col;

    float a0 = 0.f, a1 = 0.f, a2 = 0.f, a3 = 0.f;
    for (int k = 0; k < kchunk; k += 8) {
        #pragma unroll
        for (int u = 0; u < 8; ++u) {
            const float w = wp[(size_t)(k + u) * NO];
            a0 = fmaf(xp0[k + u], w, a0);
            a1 = fmaf(xp1[k + u], w, a1);
            a2 = fmaf(xp2[k + u], w, a2);
            a3 = fmaf(xp3[k + u], w, a3);
        }
    }
    if (ks > 0) {
        part[ks - 1][0][col] = a0; part[ks - 1][1][col] = a1;
        part[ks - 1][2][col] = a2; part[ks - 1][3][col] = a3;
    }
    __syncthreads();
    if (ks == 0) {
        #pragma unroll
        for (int qd = 0; qd < KS - 1; ++qd) {
            a0 += part[qd][0][col]; a1 += part[qd][1][col];
            a2 += part[qd][2][col]; a3 += part[qd][3][col];
        }
        const float bv = bias[col];
        float o0 = a0 + bv, o1 = a1 + bv, o2 = a2 + bv, o3 = a3 + bv;
        if (doRelu) {
            o0 = fmaxf(o0, 0.f); o1 = fmaxf(o1, 0.f);
            o2 = fmaxf(o2, 0.f); o3 = fmaxf(o3, 0.f);
        }
        Y[(size_t)(r0 + 0) * NO + col] = o0;
        if (r0 + 1 < Bv) Y[(size_t)(r0 + 1) * NO + col] = o1;
        if (r0 + 2 < Bv) Y[(size_t)(r0 + 2) * NO + col] = o2;
        if (r0 + 3 < Bv) Y[(size_t)(r0 + 3) * NO + col] = o3;
    }
}

extern "C" void kernel_launch(void* const* d_in, const int* in_sizes, int n_in,
                              void* d_out, int out_size, void* d_ws, size_t ws_size,
                              hipStream_t stream)
{
    const float* node_feats = (const float*)d_in[0];
    const float* edge_feats = (const float*)d_in[1];
    const float* fpv        = (const float*)d_in[2];
    const int*   src        = (const int*)d_in[3];
    const int*   dst        = (const int*)d_in[4];
    const int*   gids       = (const int*)d_in[5];
    const float* Wm  = (const float*)d_in[6];
    const float* bm  = (const float*)d_in[7];
    const float* We  = (const float*)d_in[8];
    const float* be  = (const float*)d_in[9];
    const float* Wf  = (const float*)d_in[10];
    const float* bf  = (const float*)d_in[11];
    const float* gam = (const float*)d_in[12];
    const float* bet = (const float*)d_in[13];
    const float* mu  = (const float*)d_in[14];
    const float* var = (const float*)d_in[15];
    const float* W0  = (const float*)d_in[16];
    const float* b0  = (const float*)d_in[17];
    const float* W1  = (const float*)d_in[18];
    const float* b1  = (const float*)d_in[19];
    const float* W2  = (const float*)d_in[20];
    const float* b2  = (const float*)d_in[21];
    const int E = in_sizes[3];
    const int nblk = (E + HB - 1) / HB;   // 245 for E=500000 (must be <= 256)

    // workspace layout
    float* xbuf  = (float*)d_ws;                          // [500][288]
    float* h1    = xbuf + (size_t)NB * XDIM;              // [500][512]
    float* h2    = h1 + (size_t)NB * 512;                 // [500][512]
    int*   gkey  = (int*)(h2 + (size_t)NB * 512);         // [E]
    int*   ssrc  = gkey + E;                               // [E]
    int*   seid  = ssrc + E;                               // [E]
    int*   pbh   = seid + E;                               // [nblk][NB]
    int*   pcs   = pbh + (size_t)nblk * NB;                // [nblk][NB]
    int*   gsum  = pcs + (size_t)nblk * NB;                // [NB]
    int*   offs  = gsum + NB;                              // [NB]
    int*   tot   = offs + NB;                              // [NB]

    hipLaunchKernelGGL(hist_kernel, dim3(nblk), dim3(256), 0, stream,
                       dst, gids, gkey, pbh, E);
    hipLaunchKernelGGL(colscan_kernel, dim3(NB), dim3(256), 0, stream,
                       pbh, pcs, gsum, nblk);
    hipLaunchKernelGGL(gscan_kernel, dim3(1), dim3(512), 0, stream,
                       gsum, offs, tot);
    hipLaunchKernelGGL(scatter2_kernel, dim3(nblk), dim3(256), 0, stream,
                       gkey, src, pcs, offs, ssrc, seid, E);
    hipLaunchKernelGGL(graph_accum, dim3(NB), dim3(1024), 0, stream,
                       ssrc, seid, node_feats, edge_feats, offs, tot,
                       Wm, bm, We, be, xbuf, E);
    hipLaunchKernelGGL(fp_kernel, dim3(NB / 4), dim3(1024), 0, stream,
                       fpv, Wf, bf, gam, bet, mu, var, xbuf);
    hipLaunchKernelGGL((ffn_split<512, 2>), dim3((NB + 3) / 4), dim3(1024), 0, stream,
                       xbuf, W0, b0, h1, NB, XDIM, 1);
    hipLaunchKernelGGL((ffn_split<512, 2>), dim3((NB + 3) / 4), dim3(1024), 0, stream,
                       h1, W1, b1, h2, NB, 512, 1);
    hipLaunchKernelGGL((ffn_split<256, 4>), dim3((NB + 3) / 4), dim3(1024), 0, stream,
                       h2, W2, b2, (float*)d_out, NB, 512, 0);
}